// Round 1
// baseline (1087.767 us; speedup 1.0000x reference)
//
#include <hip/hip_runtime.h>
#include <hip/hip_bf16.h>

#define N_NODES 100000
#define N_EDGES 1600000
#define NF 64
#define EF 32

// ---------------- K0: tiny prep — v = W_w^T a (160), c = W_b . a, and
// transposed copies of W_msg sub-blocks for uniform (scalar) loads later.
__global__ __launch_bounds__(256) void k0_prep(
    const float* __restrict__ Ww, const float* __restrict__ Wb,
    const float* __restrict__ a, const float* __restrict__ Wmsg,
    float* __restrict__ v, float* __restrict__ W1T, float* __restrict__ W2T,
    float* __restrict__ WmeT) {
  int t = threadIdx.x;
  for (int j = t; j < 160; j += 256) {
    float s = 0.f;
    for (int k = 0; k < 128; ++k) s = fmaf(a[k], Ww[k * 160 + j], s);
    v[j] = s;
  }
  if (t == 0) {
    float s = 0.f;
    for (int k = 0; k < 128; ++k) s = fmaf(a[k], Wb[k], s);
    v[160] = s;  // c
  }
  for (int idx = t; idx < 64 * 64; idx += 256) {
    int j = idx >> 6, i = idx & 63;
    W1T[idx] = Wmsg[i * 160 + j];        // src block, transposed [j][i]
    W2T[idx] = Wmsg[i * 160 + 64 + j];   // dst block
  }
  for (int idx = t; idx < 32 * 64; idx += 256) {
    int j = idx >> 6, i = idx & 63;
    WmeT[idx] = Wmsg[i * 160 + 128 + j]; // edge block
  }
}

// ---------------- K1: per-node precompute — s1, s2 scalars and
// m_src = W1 @ nf, m_dst = W2 @ nf (thread per node, W cols via s_load).
__global__ __launch_bounds__(256) void k1_node(
    const float* __restrict__ nf_g, const float* __restrict__ v,
    const float* __restrict__ W1T, const float* __restrict__ W2T,
    float* __restrict__ s1, float* __restrict__ s2,
    float* __restrict__ m_src, float* __restrict__ m_dst) {
  int n = blockIdx.x * 256 + threadIdx.x;
  if (n >= N_NODES) return;
  const float* nf = nf_g + (size_t)n * NF;
  float acc[64];
#pragma unroll
  for (int i = 0; i < 64; ++i) acc[i] = 0.f;
  float s1a = 0.f, s2a = 0.f;
  for (int j = 0; j < 64; ++j) {
    float x = nf[j];
    s1a = fmaf(v[j], x, s1a);
    s2a = fmaf(v[64 + j], x, s2a);
    const float* w = W1T + j * 64;
#pragma unroll
    for (int i = 0; i < 64; ++i) acc[i] = fmaf(w[i], x, acc[i]);
  }
  s1[n] = s1a;
  s2[n] = s2a;
  float* ms = m_src + (size_t)n * NF;
#pragma unroll
  for (int i = 0; i < 64; ++i) ms[i] = acc[i];
#pragma unroll
  for (int i = 0; i < 64; ++i) acc[i] = 0.f;
  for (int j = 0; j < 64; ++j) {
    float x = nf[j];
    const float* w = W2T + j * 64;
#pragma unroll
    for (int i = 0; i < 64; ++i) acc[i] = fmaf(w[i], x, acc[i]);
  }
  float* md = m_dst + (size_t)n * NF;
#pragma unroll
  for (int i = 0; i < 64; ++i) md[i] = acc[i];
}

// ---------------- K2: CSR build by dst
__global__ __launch_bounds__(256) void k2_count(const int* __restrict__ dst,
                                                int* __restrict__ cnt) {
  int e = blockIdx.x * 256 + threadIdx.x;
  if (e < N_EDGES) atomicAdd(&cnt[dst[e]], 1);
}

__global__ __launch_bounds__(1024) void k2_scan(const int* __restrict__ cnt,
                                                int* __restrict__ row_ptr,
                                                int* __restrict__ cursor) {
  __shared__ int sh[1024];
  int t = threadIdx.x;
  const int CH = (N_NODES + 1023) / 1024;  // 98
  int lo = t * CH;
  int hi = lo + CH;
  if (hi > N_NODES) hi = N_NODES;
  if (lo > N_NODES) lo = N_NODES;
  int s = 0;
  for (int i = lo; i < hi; ++i) s += cnt[i];
  sh[t] = s;
  __syncthreads();
  for (int d = 1; d < 1024; d <<= 1) {
    int val = (t >= d) ? sh[t - d] : 0;
    __syncthreads();
    sh[t] += val;
    __syncthreads();
  }
  int run = (t == 0) ? 0 : sh[t - 1];
  for (int i = lo; i < hi; ++i) {
    row_ptr[i] = run;
    cursor[i] = run;
    run += cnt[i];
  }
  if (t == 1023) row_ptr[N_NODES] = sh[1023];
}

__global__ __launch_bounds__(256) void k2_scatter(const int* __restrict__ dst,
                                                  int* __restrict__ cursor,
                                                  int* __restrict__ eid) {
  int e = blockIdx.x * 256 + threadIdx.x;
  if (e < N_EDGES) {
    int p = atomicAdd(&cursor[dst[e]], 1);
    eid[p] = e;
  }
}

// ---------------- K3: one wave per dst node — unnormalized edge softmax +
// weighted aggregation + epilogue (W_me matvec via shuffles), writes out.
__global__ __launch_bounds__(256) void k3_agg(
    const int* __restrict__ row_ptr, const int* __restrict__ eid,
    const int* __restrict__ src, const float* __restrict__ e_feat,
    const float* __restrict__ s1, const float* __restrict__ s2,
    const float* __restrict__ m_src, const float* __restrict__ m_dst,
    const float* __restrict__ v, const float* __restrict__ WmeT,
    const float* __restrict__ Wmsg_b, float* __restrict__ out) {
  int lane = threadIdx.x & 63;
  int wid = threadIdx.x >> 6;
  int n = blockIdx.x * 4 + wid;
  if (n >= N_NODES) return;
  int start = row_ptr[n];
  int end = row_ptr[n + 1];
  float v3 = v[128 + (lane & 31)];
  float c = v[160];
  float s2v = s2[n];
  float acc_ms = 0.f, acc_ef = 0.f, sum_ex = 0.f;
  for (int k = start; k < end; ++k) {
    int e = eid[k];
    int sn = src[e];
    float efv = e_feat[(size_t)e * EF + (lane & 31)];
    float msv = m_src[(size_t)sn * NF + lane];
    float t = efv * v3;
    t += __shfl_xor(t, 1);
    t += __shfl_xor(t, 2);
    t += __shfl_xor(t, 4);
    t += __shfl_xor(t, 8);
    t += __shfl_xor(t, 16);
    float lg = s1[sn] + s2v + t + c;
    float l = lg > 0.f ? lg : 0.01f * lg;  // leaky_relu(0.01)
    float ex = __expf(l);
    sum_ex += ex;
    acc_ms = fmaf(ex, msv, acc_ms);
    acc_ef = fmaf(ex, efv, acc_ef);
  }
  // mm[lane] = sum_j Wme[lane][j] * acc_ef[j]  (acc_ef[j] lives on lane j)
  float mm = 0.f;
#pragma unroll
  for (int j = 0; j < 32; ++j) {
    float efj = __shfl(acc_ef, j);
    mm = fmaf(WmeT[j * 64 + lane], efj, mm);
  }
  float o = 0.f;
  if (sum_ex > 0.f) {
    o = (acc_ms + mm) / sum_ex + m_dst[(size_t)n * NF + lane] + Wmsg_b[lane];
    o = fmaxf(o, 0.f);
  }
  out[(size_t)n * NF + lane] = o;
}

extern "C" void kernel_launch(void* const* d_in, const int* in_sizes, int n_in,
                              void* d_out, int out_size, void* d_ws,
                              size_t ws_size, hipStream_t stream) {
  const float* n_feat = (const float*)d_in[0];
  const float* e_feat = (const float*)d_in[1];
  const int* src = (const int*)d_in[2];
  const int* dst = (const int*)d_in[3];
  const float* Wmsg_w = (const float*)d_in[4];
  const float* Wmsg_b = (const float*)d_in[5];
  const float* W_w = (const float*)d_in[6];
  const float* W_b = (const float*)d_in[7];
  const float* a = (const float*)d_in[8];
  float* out = (float*)d_out;

  char* ws = (char*)d_ws;
  size_t off = 0;
  auto alloc = [&](size_t bytes) -> char* {
    char* p = ws + off;
    off = (off + bytes + 255) & ~(size_t)255;
    return p;
  };
  float* v = (float*)alloc(161 * 4);
  float* W1T = (float*)alloc(64 * 64 * 4);
  float* W2T = (float*)alloc(64 * 64 * 4);
  float* WmeT = (float*)alloc(32 * 64 * 4);
  float* s1 = (float*)alloc(N_NODES * 4);
  float* s2 = (float*)alloc(N_NODES * 4);
  float* m_src = (float*)alloc((size_t)N_NODES * NF * 4);
  float* m_dst = (float*)alloc((size_t)N_NODES * NF * 4);
  int* cnt = (int*)alloc(N_NODES * 4);
  int* row_ptr = (int*)alloc((N_NODES + 1) * 4);
  int* cursor = (int*)alloc(N_NODES * 4);
  int* eid = (int*)alloc((size_t)N_EDGES * 4);
  if (off > ws_size) return;  // workspace too small — fail loudly in check

  k0_prep<<<1, 256, 0, stream>>>(W_w, W_b, a, Wmsg_w, v, W1T, W2T, WmeT);
  k1_node<<<(N_NODES + 255) / 256, 256, 0, stream>>>(n_feat, v, W1T, W2T, s1,
                                                     s2, m_src, m_dst);
  hipMemsetAsync(cnt, 0, N_NODES * 4, stream);
  k2_count<<<(N_EDGES + 255) / 256, 256, 0, stream>>>(dst, cnt);
  k2_scan<<<1, 1024, 0, stream>>>(cnt, row_ptr, cursor);
  k2_scatter<<<(N_EDGES + 255) / 256, 256, 0, stream>>>(dst, cursor, eid);
  k3_agg<<<(N_NODES + 3) / 4, 256, 0, stream>>>(row_ptr, eid, src, e_feat, s1,
                                                s2, m_src, m_dst, v, WmeT,
                                                Wmsg_b, out);
}

// Round 2
// 862.414 us; speedup vs baseline: 1.2613x; 1.2613x over previous
//
#include <hip/hip_runtime.h>
#include <hip/hip_bf16.h>

#define N_NODES 100000
#define N_EDGES 1600000
#define NF 64
#define EF 32

// ---------------- K0: tiny prep — v = W_w^T a (160), c = W_b . a, and
// transposed copies of W_msg sub-blocks.
__global__ __launch_bounds__(256) void k0_prep(
    const float* __restrict__ Ww, const float* __restrict__ Wb,
    const float* __restrict__ a, const float* __restrict__ Wmsg,
    float* __restrict__ v, float* __restrict__ W1T, float* __restrict__ W2T,
    float* __restrict__ WmeT) {
  int t = threadIdx.x;
  for (int j = t; j < 160; j += 256) {
    float s = 0.f;
    for (int k = 0; k < 128; ++k) s = fmaf(a[k], Ww[k * 160 + j], s);
    v[j] = s;
  }
  if (t == 0) {
    float s = 0.f;
    for (int k = 0; k < 128; ++k) s = fmaf(a[k], Wb[k], s);
    v[160] = s;  // c
  }
  for (int idx = t; idx < 64 * 64; idx += 256) {
    int j = idx >> 6, i = idx & 63;
    W1T[idx] = Wmsg[i * 160 + j];        // src block, transposed [j][i]
    W2T[idx] = Wmsg[i * 160 + 64 + j];   // dst block
  }
  for (int idx = t; idx < 32 * 64; idx += 256) {
    int j = idx >> 6, i = idx & 63;
    WmeT[idx] = Wmsg[i * 160 + 128 + j]; // edge block
  }
}

// ---------------- K1: per-node precompute — s1, s2 scalars and
// m_src = W1 @ nf, m_dst = W2 @ nf (thread per node, float4 nf loads).
__global__ __launch_bounds__(256) void k1_node(
    const float* __restrict__ nf_g, const float* __restrict__ v,
    const float* __restrict__ W1T, const float* __restrict__ W2T,
    float* __restrict__ s1, float* __restrict__ s2,
    float* __restrict__ m_src, float* __restrict__ m_dst) {
  int n = blockIdx.x * 256 + threadIdx.x;
  if (n >= N_NODES) return;
  const float4* nf4 = (const float4*)(nf_g + (size_t)n * NF);
  float acc[64];
#pragma unroll
  for (int i = 0; i < 64; ++i) acc[i] = 0.f;
  float s1a = 0.f, s2a = 0.f;
  for (int j4 = 0; j4 < 16; ++j4) {
    float4 q = nf4[j4];
    float xs[4] = {q.x, q.y, q.z, q.w};
#pragma unroll
    for (int u = 0; u < 4; ++u) {
      int j = j4 * 4 + u;
      float x = xs[u];
      s1a = fmaf(v[j], x, s1a);
      s2a = fmaf(v[64 + j], x, s2a);
      const float* w = W1T + j * 64;
#pragma unroll
      for (int i = 0; i < 64; ++i) acc[i] = fmaf(w[i], x, acc[i]);
    }
  }
  s1[n] = s1a;
  s2[n] = s2a;
  float* ms = m_src + (size_t)n * NF;
#pragma unroll
  for (int i = 0; i < 64; ++i) ms[i] = acc[i];
#pragma unroll
  for (int i = 0; i < 64; ++i) acc[i] = 0.f;
  for (int j4 = 0; j4 < 16; ++j4) {
    float4 q = nf4[j4];
    float xs[4] = {q.x, q.y, q.z, q.w};
#pragma unroll
    for (int u = 0; u < 4; ++u) {
      int j = j4 * 4 + u;
      float x = xs[u];
      const float* w = W2T + j * 64;
#pragma unroll
      for (int i = 0; i < 64; ++i) acc[i] = fmaf(w[i], x, acc[i]);
    }
  }
  float* md = m_dst + (size_t)n * NF;
#pragma unroll
  for (int i = 0; i < 64; ++i) md[i] = acc[i];
}

// ---------------- KE: edge-parallel — ex[e] = exp(leaky(logit)) fully
// precomputed (s1/s2 gathers hit small L2-resident tables), fused with the
// CSR degree count so dst is read once.
__global__ __launch_bounds__(256) void kE_edge(
    const int* __restrict__ src, const int* __restrict__ dst,
    const float* __restrict__ e_feat, const float* __restrict__ s1,
    const float* __restrict__ s2, const float* __restrict__ v,
    float* __restrict__ ex_out, int* __restrict__ cnt) {
  int e = blockIdx.x * 256 + threadIdx.x;
  if (e >= N_EDGES) return;
  int sn = src[e], dn = dst[e];
  const float4* efr = (const float4*)(e_feat + (size_t)e * EF);
  float t = 0.f;
#pragma unroll
  for (int i = 0; i < 8; ++i) {
    float4 q = efr[i];
    t = fmaf(q.x, v[128 + i * 4 + 0], t);
    t = fmaf(q.y, v[128 + i * 4 + 1], t);
    t = fmaf(q.z, v[128 + i * 4 + 2], t);
    t = fmaf(q.w, v[128 + i * 4 + 3], t);
  }
  float lg = s1[sn] + s2[dn] + t + v[160];
  float l = lg > 0.f ? lg : 0.01f * lg;  // leaky_relu(0.01)
  ex_out[e] = __expf(l);
  atomicAdd(&cnt[dn], 1);
}

// ---------------- K2: scan + scatter (packed int4 {e, src, ex} per slot)
__global__ __launch_bounds__(1024) void k2_scan(const int* __restrict__ cnt,
                                                int* __restrict__ row_ptr,
                                                int* __restrict__ cursor) {
  __shared__ int sh[1024];
  int t = threadIdx.x;
  const int CH = (N_NODES + 1023) / 1024;  // 98
  int lo = t * CH;
  int hi = lo + CH;
  if (hi > N_NODES) hi = N_NODES;
  if (lo > N_NODES) lo = N_NODES;
  int s = 0;
  for (int i = lo; i < hi; ++i) s += cnt[i];
  sh[t] = s;
  __syncthreads();
  for (int d = 1; d < 1024; d <<= 1) {
    int val = (t >= d) ? sh[t - d] : 0;
    __syncthreads();
    sh[t] += val;
    __syncthreads();
  }
  int run = (t == 0) ? 0 : sh[t - 1];
  for (int i = lo; i < hi; ++i) {
    row_ptr[i] = run;
    cursor[i] = run;
    run += cnt[i];
  }
  if (t == 1023) row_ptr[N_NODES] = sh[1023];
}

__global__ __launch_bounds__(256) void k2_scatter(
    const int* __restrict__ dst, const int* __restrict__ src,
    const float* __restrict__ ex, int* __restrict__ cursor,
    int4* __restrict__ edata) {
  int e = blockIdx.x * 256 + threadIdx.x;
  if (e < N_EDGES) {
    int dn = dst[e];
    int p = atomicAdd(&cursor[dn], 1);
    edata[p] = make_int4(e, src[e], __float_as_int(ex[e]), 0);
  }
}

// ---------------- K3: one wave per dst node. Chunk-load 64 edges' packed
// metadata (one coalesced 16B load), then groups of 4 edges with all 8
// gathers issued before consumption. No exp, no scalar-table gathers.
__global__ __launch_bounds__(256) void k3_agg(
    const int* __restrict__ row_ptr, const int4* __restrict__ edata,
    const float* __restrict__ e_feat, const float* __restrict__ m_src,
    const float* __restrict__ m_dst, const float* __restrict__ WmeT,
    const float* __restrict__ Wmsg_b, float* __restrict__ out) {
  int lane = threadIdx.x & 63;
  int wid = threadIdx.x >> 6;
  int n = blockIdx.x * 4 + wid;
  if (n >= N_NODES) return;
  int start = row_ptr[n];
  int end = row_ptr[n + 1];
  float sum_ex = 0.f, acc_ms = 0.f, acc_ef = 0.f;
  for (int base = start; base < end; base += 64) {
    int4 md = make_int4(0, 0, 0, 0);  // ex=0 pad: contributes nothing
    if (base + lane < end) md = edata[base + lane];
    int m = end - base;
    if (m > 64) m = 64;
    int mm4 = (m + 3) & ~3;
    for (int k = 0; k < mm4; k += 4) {
      int ek[4], sk[4];
      float exk[4], efk[4], msk[4];
#pragma unroll
      for (int u = 0; u < 4; ++u) {
        ek[u] = __shfl(md.x, k + u);
        sk[u] = __shfl(md.y, k + u);
        exk[u] = __int_as_float(__shfl(md.z, k + u));
      }
#pragma unroll
      for (int u = 0; u < 4; ++u) {
        efk[u] = e_feat[(size_t)ek[u] * EF + (lane & 31)];
        msk[u] = m_src[(size_t)sk[u] * NF + lane];
      }
#pragma unroll
      for (int u = 0; u < 4; ++u) {
        sum_ex += exk[u];
        acc_ms = fmaf(exk[u], msk[u], acc_ms);
        acc_ef = fmaf(exk[u], efk[u], acc_ef);
      }
    }
  }
  // mm[lane] = sum_j Wme[lane][j] * acc_ef[j]  (acc_ef[j] lives on lane j)
  float mm = 0.f;
#pragma unroll
  for (int j = 0; j < 32; ++j) {
    float efj = __shfl(acc_ef, j);
    mm = fmaf(WmeT[j * 64 + lane], efj, mm);
  }
  float o = 0.f;
  if (sum_ex > 0.f) {
    o = (acc_ms + mm) / sum_ex + m_dst[(size_t)n * NF + lane] + Wmsg_b[lane];
    o = fmaxf(o, 0.f);
  }
  out[(size_t)n * NF + lane] = o;
}

extern "C" void kernel_launch(void* const* d_in, const int* in_sizes, int n_in,
                              void* d_out, int out_size, void* d_ws,
                              size_t ws_size, hipStream_t stream) {
  const float* n_feat = (const float*)d_in[0];
  const float* e_feat = (const float*)d_in[1];
  const int* src = (const int*)d_in[2];
  const int* dst = (const int*)d_in[3];
  const float* Wmsg_w = (const float*)d_in[4];
  const float* Wmsg_b = (const float*)d_in[5];
  const float* W_w = (const float*)d_in[6];
  const float* W_b = (const float*)d_in[7];
  const float* a = (const float*)d_in[8];
  float* out = (float*)d_out;

  char* ws = (char*)d_ws;
  size_t off = 0;
  auto alloc = [&](size_t bytes) -> char* {
    char* p = ws + off;
    off = (off + bytes + 255) & ~(size_t)255;
    return p;
  };
  float* v = (float*)alloc(161 * 4);
  float* W1T = (float*)alloc(64 * 64 * 4);
  float* W2T = (float*)alloc(64 * 64 * 4);
  float* WmeT = (float*)alloc(32 * 64 * 4);
  float* s1 = (float*)alloc(N_NODES * 4);
  float* s2 = (float*)alloc(N_NODES * 4);
  float* m_src = (float*)alloc((size_t)N_NODES * NF * 4);
  float* m_dst = (float*)alloc((size_t)N_NODES * NF * 4);
  int* cnt = (int*)alloc(N_NODES * 4);
  int* row_ptr = (int*)alloc((N_NODES + 1) * 4);
  int* cursor = (int*)alloc(N_NODES * 4);
  float* ex = (float*)alloc((size_t)N_EDGES * 4);
  int4* edata = (int4*)alloc((size_t)N_EDGES * 16);
  if (off > ws_size) return;  // workspace too small — fail loudly in check

  k0_prep<<<1, 256, 0, stream>>>(W_w, W_b, a, Wmsg_w, v, W1T, W2T, WmeT);
  k1_node<<<(N_NODES + 255) / 256, 256, 0, stream>>>(n_feat, v, W1T, W2T, s1,
                                                     s2, m_src, m_dst);
  hipMemsetAsync(cnt, 0, N_NODES * 4, stream);
  kE_edge<<<(N_EDGES + 255) / 256, 256, 0, stream>>>(src, dst, e_feat, s1, s2,
                                                     v, ex, cnt);
  k2_scan<<<1, 1024, 0, stream>>>(cnt, row_ptr, cursor);
  k2_scatter<<<(N_EDGES + 255) / 256, 256, 0, stream>>>(dst, src, ex, cursor,
                                                        edata);
  k3_agg<<<(N_NODES + 3) / 4, 256, 0, stream>>>(row_ptr, edata, e_feat, m_src,
                                                m_dst, WmeT, Wmsg_b, out);
}

// Round 3
// 637.006 us; speedup vs baseline: 1.7076x; 1.3539x over previous
//
#include <hip/hip_runtime.h>
#include <hip/hip_bf16.h>

#define N_NODES 100000
#define N_EDGES 1600000
#define NF 64
#define EF 32

#define SCAN_B 512
#define SCAN_NB ((N_NODES + SCAN_B - 1) / SCAN_B)  // 196

// ---------------- K0: tiny prep — v = W_w^T a (160), c = W_b . a, and
// transposed copies of W_msg sub-blocks.
__global__ __launch_bounds__(256) void k0_prep(
    const float* __restrict__ Ww, const float* __restrict__ Wb,
    const float* __restrict__ a, const float* __restrict__ Wmsg,
    float* __restrict__ v, float* __restrict__ W1T, float* __restrict__ W2T,
    float* __restrict__ WmeT) {
  int t = threadIdx.x;
  for (int j = t; j < 160; j += 256) {
    float s = 0.f;
    for (int k = 0; k < 128; ++k) s = fmaf(a[k], Ww[k * 160 + j], s);
    v[j] = s;
  }
  if (t == 0) {
    float s = 0.f;
    for (int k = 0; k < 128; ++k) s = fmaf(a[k], Wb[k], s);
    v[160] = s;  // c
  }
  for (int idx = t; idx < 64 * 64; idx += 256) {
    int j = idx >> 6, i = idx & 63;
    W1T[idx] = Wmsg[i * 160 + j];        // src block, transposed [j][i]
    W2T[idx] = Wmsg[i * 160 + 64 + j];   // dst block
  }
  for (int idx = t; idx < 32 * 64; idx += 256) {
    int j = idx >> 6, i = idx & 63;
    WmeT[idx] = Wmsg[i * 160 + 128 + j]; // edge block
  }
}

// ---------------- K1: per-node precompute — s1, s2 scalars and
// m_src = W1 @ nf, m_dst = W2 @ nf (thread per node, float4 nf loads).
__global__ __launch_bounds__(256) void k1_node(
    const float* __restrict__ nf_g, const float* __restrict__ v,
    const float* __restrict__ W1T, const float* __restrict__ W2T,
    float* __restrict__ s1, float* __restrict__ s2,
    float* __restrict__ m_src, float* __restrict__ m_dst) {
  int n = blockIdx.x * 256 + threadIdx.x;
  if (n >= N_NODES) return;
  const float4* nf4 = (const float4*)(nf_g + (size_t)n * NF);
  float acc[64];
#pragma unroll
  for (int i = 0; i < 64; ++i) acc[i] = 0.f;
  float s1a = 0.f, s2a = 0.f;
  for (int j4 = 0; j4 < 16; ++j4) {
    float4 q = nf4[j4];
    float xs[4] = {q.x, q.y, q.z, q.w};
#pragma unroll
    for (int u = 0; u < 4; ++u) {
      int j = j4 * 4 + u;
      float x = xs[u];
      s1a = fmaf(v[j], x, s1a);
      s2a = fmaf(v[64 + j], x, s2a);
      const float* w = W1T + j * 64;
#pragma unroll
      for (int i = 0; i < 64; ++i) acc[i] = fmaf(w[i], x, acc[i]);
    }
  }
  s1[n] = s1a;
  s2[n] = s2a;
  float* ms = m_src + (size_t)n * NF;
#pragma unroll
  for (int i = 0; i < 64; ++i) ms[i] = acc[i];
#pragma unroll
  for (int i = 0; i < 64; ++i) acc[i] = 0.f;
  for (int j4 = 0; j4 < 16; ++j4) {
    float4 q = nf4[j4];
    float xs[4] = {q.x, q.y, q.z, q.w};
#pragma unroll
    for (int u = 0; u < 4; ++u) {
      int j = j4 * 4 + u;
      float x = xs[u];
      const float* w = W2T + j * 64;
#pragma unroll
      for (int i = 0; i < 64; ++i) acc[i] = fmaf(w[i], x, acc[i]);
    }
  }
  float* md = m_dst + (size_t)n * NF;
#pragma unroll
  for (int i = 0; i < 64; ++i) md[i] = acc[i];
}

// ---------------- KE: edge-parallel — ex[e] = exp(leaky(logit)) fully
// precomputed, fused with CSR degree count.
__global__ __launch_bounds__(256) void kE_edge(
    const int* __restrict__ src, const int* __restrict__ dst,
    const float* __restrict__ e_feat, const float* __restrict__ s1,
    const float* __restrict__ s2, const float* __restrict__ v,
    float* __restrict__ ex_out, int* __restrict__ cnt) {
  int e = blockIdx.x * 256 + threadIdx.x;
  if (e >= N_EDGES) return;
  int sn = src[e], dn = dst[e];
  const float4* efr = (const float4*)(e_feat + (size_t)e * EF);
  float t = 0.f;
#pragma unroll
  for (int i = 0; i < 8; ++i) {
    float4 q = efr[i];
    t = fmaf(q.x, v[128 + i * 4 + 0], t);
    t = fmaf(q.y, v[128 + i * 4 + 1], t);
    t = fmaf(q.z, v[128 + i * 4 + 2], t);
    t = fmaf(q.w, v[128 + i * 4 + 3], t);
  }
  float lg = s1[sn] + s2[dn] + t + v[160];
  float l = lg > 0.f ? lg : 0.01f * lg;  // leaky_relu(0.01)
  ex_out[e] = __expf(l);
  atomicAdd(&cnt[dn], 1);
}

// ---------------- hierarchical scan: kS1 (block reduce) -> kS2 (scan block
// sums, 1 tiny block) -> kS3 (intra-block scan + offset, write row_ptr/cursor)
__global__ __launch_bounds__(SCAN_B) void kS1(const int* __restrict__ cnt,
                                              int* __restrict__ bsum) {
  __shared__ int sh[SCAN_B];
  int t = threadIdx.x;
  int i = blockIdx.x * SCAN_B + t;
  sh[t] = (i < N_NODES) ? cnt[i] : 0;
  __syncthreads();
  for (int d = SCAN_B / 2; d > 0; d >>= 1) {
    if (t < d) sh[t] += sh[t + d];
    __syncthreads();
  }
  if (t == 0) bsum[blockIdx.x] = sh[0];
}

__global__ __launch_bounds__(256) void kS2(const int* __restrict__ bsum,
                                           int* __restrict__ boff,
                                           int* __restrict__ row_ptr) {
  __shared__ int sh[256];
  int t = threadIdx.x;
  sh[t] = (t < SCAN_NB) ? bsum[t] : 0;
  __syncthreads();
  for (int d = 1; d < 256; d <<= 1) {
    int val = (t >= d) ? sh[t - d] : 0;
    __syncthreads();
    sh[t] += val;
    __syncthreads();
  }
  if (t < SCAN_NB) boff[t] = (t == 0) ? 0 : sh[t - 1];
  if (t == 255) row_ptr[N_NODES] = sh[255];
}

__global__ __launch_bounds__(SCAN_B) void kS3(const int* __restrict__ cnt,
                                              const int* __restrict__ boff,
                                              int* __restrict__ row_ptr,
                                              int* __restrict__ cursor) {
  __shared__ int sh[SCAN_B];
  int t = threadIdx.x;
  int i = blockIdx.x * SCAN_B + t;
  int val = (i < N_NODES) ? cnt[i] : 0;
  sh[t] = val;
  __syncthreads();
  for (int d = 1; d < SCAN_B; d <<= 1) {
    int u = (t >= d) ? sh[t - d] : 0;
    __syncthreads();
    sh[t] += u;
    __syncthreads();
  }
  if (i < N_NODES) {
    int excl = boff[blockIdx.x] + sh[t] - val;
    row_ptr[i] = excl;
    cursor[i] = excl;
  }
}

__global__ __launch_bounds__(256) void k2_scatter(
    const int* __restrict__ dst, const int* __restrict__ src,
    const float* __restrict__ ex, int* __restrict__ cursor,
    int4* __restrict__ edata) {
  int e = blockIdx.x * 256 + threadIdx.x;
  if (e < N_EDGES) {
    int dn = dst[e];
    int p = atomicAdd(&cursor[dn], 1);
    edata[p] = make_int4(e, src[e], __float_as_int(ex[e]), 0);
  }
}

// ---------------- K3: one wave per dst node. Chunk-load 64 edges' packed
// metadata, then groups of 4 edges with all 8 gathers issued before use.
__global__ __launch_bounds__(256) void k3_agg(
    const int* __restrict__ row_ptr, const int4* __restrict__ edata,
    const float* __restrict__ e_feat, const float* __restrict__ m_src,
    const float* __restrict__ m_dst, const float* __restrict__ WmeT,
    const float* __restrict__ Wmsg_b, float* __restrict__ out) {
  int lane = threadIdx.x & 63;
  int wid = threadIdx.x >> 6;
  int n = blockIdx.x * 4 + wid;
  if (n >= N_NODES) return;
  int start = row_ptr[n];
  int end = row_ptr[n + 1];
  float sum_ex = 0.f, acc_ms = 0.f, acc_ef = 0.f;
  for (int base = start; base < end; base += 64) {
    int4 md = make_int4(0, 0, 0, 0);  // ex=0 pad: contributes nothing
    if (base + lane < end) md = edata[base + lane];
    int m = end - base;
    if (m > 64) m = 64;
    int mm4 = (m + 3) & ~3;
    for (int k = 0; k < mm4; k += 4) {
      int ek[4], sk[4];
      float exk[4], efk[4], msk[4];
#pragma unroll
      for (int u = 0; u < 4; ++u) {
        ek[u] = __shfl(md.x, k + u);
        sk[u] = __shfl(md.y, k + u);
        exk[u] = __int_as_float(__shfl(md.z, k + u));
      }
#pragma unroll
      for (int u = 0; u < 4; ++u) {
        efk[u] = e_feat[(size_t)ek[u] * EF + (lane & 31)];
        msk[u] = m_src[(size_t)sk[u] * NF + lane];
      }
#pragma unroll
      for (int u = 0; u < 4; ++u) {
        sum_ex += exk[u];
        acc_ms = fmaf(exk[u], msk[u], acc_ms);
        acc_ef = fmaf(exk[u], efk[u], acc_ef);
      }
    }
  }
  float mm = 0.f;
#pragma unroll
  for (int j = 0; j < 32; ++j) {
    float efj = __shfl(acc_ef, j);
    mm = fmaf(WmeT[j * 64 + lane], efj, mm);
  }
  float o = 0.f;
  if (sum_ex > 0.f) {
    o = (acc_ms + mm) / sum_ex + m_dst[(size_t)n * NF + lane] + Wmsg_b[lane];
    o = fmaxf(o, 0.f);
  }
  out[(size_t)n * NF + lane] = o;
}

extern "C" void kernel_launch(void* const* d_in, const int* in_sizes, int n_in,
                              void* d_out, int out_size, void* d_ws,
                              size_t ws_size, hipStream_t stream) {
  const float* n_feat = (const float*)d_in[0];
  const float* e_feat = (const float*)d_in[1];
  const int* src = (const int*)d_in[2];
  const int* dst = (const int*)d_in[3];
  const float* Wmsg_w = (const float*)d_in[4];
  const float* Wmsg_b = (const float*)d_in[5];
  const float* W_w = (const float*)d_in[6];
  const float* W_b = (const float*)d_in[7];
  const float* a = (const float*)d_in[8];
  float* out = (float*)d_out;

  char* ws = (char*)d_ws;
  size_t off = 0;
  auto alloc = [&](size_t bytes) -> char* {
    char* p = ws + off;
    off = (off + bytes + 255) & ~(size_t)255;
    return p;
  };
  float* v = (float*)alloc(161 * 4);
  float* W1T = (float*)alloc(64 * 64 * 4);
  float* W2T = (float*)alloc(64 * 64 * 4);
  float* WmeT = (float*)alloc(32 * 64 * 4);
  float* s1 = (float*)alloc(N_NODES * 4);
  float* s2 = (float*)alloc(N_NODES * 4);
  float* m_src = (float*)alloc((size_t)N_NODES * NF * 4);
  float* m_dst = (float*)alloc((size_t)N_NODES * NF * 4);
  int* cnt = (int*)alloc(N_NODES * 4);
  int* row_ptr = (int*)alloc((N_NODES + 1) * 4);
  int* cursor = (int*)alloc(N_NODES * 4);
  int* bsum = (int*)alloc(SCAN_NB * 4);
  int* boff = (int*)alloc(SCAN_NB * 4);
  float* ex = (float*)alloc((size_t)N_EDGES * 4);
  int4* edata = (int4*)alloc((size_t)N_EDGES * 16);
  if (off > ws_size) return;  // workspace too small — fail loudly in check

  k0_prep<<<1, 256, 0, stream>>>(W_w, W_b, a, Wmsg_w, v, W1T, W2T, WmeT);
  k1_node<<<(N_NODES + 255) / 256, 256, 0, stream>>>(n_feat, v, W1T, W2T, s1,
                                                     s2, m_src, m_dst);
  hipMemsetAsync(cnt, 0, N_NODES * 4, stream);
  kE_edge<<<(N_EDGES + 255) / 256, 256, 0, stream>>>(src, dst, e_feat, s1, s2,
                                                     v, ex, cnt);
  kS1<<<SCAN_NB, SCAN_B, 0, stream>>>(cnt, bsum);
  kS2<<<1, 256, 0, stream>>>(bsum, boff, row_ptr);
  kS3<<<SCAN_NB, SCAN_B, 0, stream>>>(cnt, boff, row_ptr, cursor);
  k2_scatter<<<(N_EDGES + 255) / 256, 256, 0, stream>>>(dst, src, ex, cursor,
                                                        edata);
  k3_agg<<<(N_NODES + 3) / 4, 256, 0, stream>>>(row_ptr, edata, e_feat, m_src,
                                                m_dst, WmeT, Wmsg_b, out);
}

// Round 4
// 627.701 us; speedup vs baseline: 1.7329x; 1.0148x over previous
//
#include <hip/hip_runtime.h>
#include <hip/hip_bf16.h>

#define N_NODES 100000
#define N_EDGES 1600000
#define NF 64
#define EF 32

#define SCAN_B 512
#define SCAN_NB ((N_NODES + SCAN_B - 1) / SCAN_B)  // 196

// packed edge record (8B): [63:43]=e (21b) [42:26]=src (17b) [25:0]=ex_bits>>6
// ex is exp(..)>0 so sign bit is 0; keeping exp8+mant17 -> rel err <= 2^-17.

// ---------------- K0: tiny prep — v = W_w^T a (160), c = W_b . a, and
// transposed copies of W_msg sub-blocks.
__global__ __launch_bounds__(256) void k0_prep(
    const float* __restrict__ Ww, const float* __restrict__ Wb,
    const float* __restrict__ a, const float* __restrict__ Wmsg,
    float* __restrict__ v, float* __restrict__ W1T, float* __restrict__ W2T,
    float* __restrict__ WmeT) {
  int t = threadIdx.x;
  for (int j = t; j < 160; j += 256) {
    float s = 0.f;
    for (int k = 0; k < 128; ++k) s = fmaf(a[k], Ww[k * 160 + j], s);
    v[j] = s;
  }
  if (t == 0) {
    float s = 0.f;
    for (int k = 0; k < 128; ++k) s = fmaf(a[k], Wb[k], s);
    v[160] = s;  // c
  }
  for (int idx = t; idx < 64 * 64; idx += 256) {
    int j = idx >> 6, i = idx & 63;
    W1T[idx] = Wmsg[i * 160 + j];        // src block, transposed [j][i]
    W2T[idx] = Wmsg[i * 160 + 64 + j];   // dst block
  }
  for (int idx = t; idx < 32 * 64; idx += 256) {
    int j = idx >> 6, i = idx & 63;
    WmeT[idx] = Wmsg[i * 160 + 128 + j]; // edge block
  }
}

// ---------------- K1: per-node precompute — s1, s2 scalars and
// m_src = W1 @ nf, m_dst = W2 @ nf (thread per node, float4 nf loads).
__global__ __launch_bounds__(256) void k1_node(
    const float* __restrict__ nf_g, const float* __restrict__ v,
    const float* __restrict__ W1T, const float* __restrict__ W2T,
    float* __restrict__ s1, float* __restrict__ s2,
    float* __restrict__ m_src, float* __restrict__ m_dst) {
  int n = blockIdx.x * 256 + threadIdx.x;
  if (n >= N_NODES) return;
  const float4* nf4 = (const float4*)(nf_g + (size_t)n * NF);
  float acc[64];
#pragma unroll
  for (int i = 0; i < 64; ++i) acc[i] = 0.f;
  float s1a = 0.f, s2a = 0.f;
  for (int j4 = 0; j4 < 16; ++j4) {
    float4 q = nf4[j4];
    float xs[4] = {q.x, q.y, q.z, q.w};
#pragma unroll
    for (int u = 0; u < 4; ++u) {
      int j = j4 * 4 + u;
      float x = xs[u];
      s1a = fmaf(v[j], x, s1a);
      s2a = fmaf(v[64 + j], x, s2a);
      const float* w = W1T + j * 64;
#pragma unroll
      for (int i = 0; i < 64; ++i) acc[i] = fmaf(w[i], x, acc[i]);
    }
  }
  s1[n] = s1a;
  s2[n] = s2a;
  float* ms = m_src + (size_t)n * NF;
#pragma unroll
  for (int i = 0; i < 64; ++i) ms[i] = acc[i];
#pragma unroll
  for (int i = 0; i < 64; ++i) acc[i] = 0.f;
  for (int j4 = 0; j4 < 16; ++j4) {
    float4 q = nf4[j4];
    float xs[4] = {q.x, q.y, q.z, q.w};
#pragma unroll
    for (int u = 0; u < 4; ++u) {
      int j = j4 * 4 + u;
      float x = xs[u];
      const float* w = W2T + j * 64;
#pragma unroll
      for (int i = 0; i < 64; ++i) acc[i] = fmaf(w[i], x, acc[i]);
    }
  }
  float* md = m_dst + (size_t)n * NF;
#pragma unroll
  for (int i = 0; i < 64; ++i) md[i] = acc[i];
}

// ---------------- degree count (reads dst only)
__global__ __launch_bounds__(256) void k_count(const int* __restrict__ dst,
                                               int* __restrict__ cnt) {
  int e = blockIdx.x * 256 + threadIdx.x;
  if (e < N_EDGES) atomicAdd(&cnt[dst[e]], 1);
}

// ---------------- hierarchical scan
__global__ __launch_bounds__(SCAN_B) void kS1(const int* __restrict__ cnt,
                                              int* __restrict__ bsum) {
  __shared__ int sh[SCAN_B];
  int t = threadIdx.x;
  int i = blockIdx.x * SCAN_B + t;
  sh[t] = (i < N_NODES) ? cnt[i] : 0;
  __syncthreads();
  for (int d = SCAN_B / 2; d > 0; d >>= 1) {
    if (t < d) sh[t] += sh[t + d];
    __syncthreads();
  }
  if (t == 0) bsum[blockIdx.x] = sh[0];
}

__global__ __launch_bounds__(256) void kS2(const int* __restrict__ bsum,
                                           int* __restrict__ boff,
                                           int* __restrict__ row_ptr) {
  __shared__ int sh[256];
  int t = threadIdx.x;
  sh[t] = (t < SCAN_NB) ? bsum[t] : 0;
  __syncthreads();
  for (int d = 1; d < 256; d <<= 1) {
    int val = (t >= d) ? sh[t - d] : 0;
    __syncthreads();
    sh[t] += val;
    __syncthreads();
  }
  if (t < SCAN_NB) boff[t] = (t == 0) ? 0 : sh[t - 1];
  if (t == 255) row_ptr[N_NODES] = sh[255];
}

__global__ __launch_bounds__(SCAN_B) void kS3(const int* __restrict__ cnt,
                                              const int* __restrict__ boff,
                                              int* __restrict__ row_ptr,
                                              int* __restrict__ cursor) {
  __shared__ int sh[SCAN_B];
  int t = threadIdx.x;
  int i = blockIdx.x * SCAN_B + t;
  int val = (i < N_NODES) ? cnt[i] : 0;
  sh[t] = val;
  __syncthreads();
  for (int d = 1; d < SCAN_B; d <<= 1) {
    int u = (t >= d) ? sh[t - d] : 0;
    __syncthreads();
    sh[t] += u;
    __syncthreads();
  }
  if (i < N_NODES) {
    int excl = boff[blockIdx.x] + sh[t] - val;
    row_ptr[i] = excl;
    cursor[i] = excl;
  }
}

// ---------------- fused: ex = exp(leaky(logit)) + packed 8B scatter
__global__ __launch_bounds__(256) void kE_scatter(
    const int* __restrict__ src, const int* __restrict__ dst,
    const float* __restrict__ e_feat, const float* __restrict__ s1,
    const float* __restrict__ s2, const float* __restrict__ v,
    int* __restrict__ cursor, unsigned long long* __restrict__ edata) {
  int e = blockIdx.x * 256 + threadIdx.x;
  if (e >= N_EDGES) return;
  int sn = src[e], dn = dst[e];
  const float4* efr = (const float4*)(e_feat + (size_t)e * EF);
  float t = 0.f;
#pragma unroll
  for (int i = 0; i < 8; ++i) {
    float4 q = efr[i];
    t = fmaf(q.x, v[128 + i * 4 + 0], t);
    t = fmaf(q.y, v[128 + i * 4 + 1], t);
    t = fmaf(q.z, v[128 + i * 4 + 2], t);
    t = fmaf(q.w, v[128 + i * 4 + 3], t);
  }
  float lg = s1[sn] + s2[dn] + t + v[160];
  float l = lg > 0.f ? lg : 0.01f * lg;  // leaky_relu(0.01)
  float ex = __expf(l);
  int p = atomicAdd(&cursor[dn], 1);
  unsigned long long pk = ((unsigned long long)(unsigned)e << 43) |
                          ((unsigned long long)(unsigned)sn << 26) |
                          (unsigned long long)(__float_as_uint(ex) >> 6);
  edata[p] = pk;
}

// ---------------- K3: one wave per dst node. 8B packed metadata chunk-load;
// groups of 4 edges: 4 m_src gathers + 2 half-wave ef gathers issued before
// any consumption.
__global__ __launch_bounds__(256) void k3_agg(
    const int* __restrict__ row_ptr, const int2* __restrict__ edata,
    const float* __restrict__ e_feat, const float* __restrict__ m_src,
    const float* __restrict__ m_dst, const float* __restrict__ WmeT,
    const float* __restrict__ Wmsg_b, float* __restrict__ out) {
  int lane = threadIdx.x & 63;
  int wid = threadIdx.x >> 6;
  int n = blockIdx.x * 4 + wid;
  if (n >= N_NODES) return;
  int start = row_ptr[n];
  int end = row_ptr[n + 1];
  int half = lane >> 5;      // 0 or 1
  int col = lane & 31;
  float sum_ex = 0.f, acc_ms = 0.f, acc_ef = 0.f;
  for (int base = start; base < end; base += 64) {
    int2 md = make_int2(0, 0);  // pk=0 -> e=0, src=0, ex=0 (pad: no contrib)
    if (base + lane < end) md = edata[base + lane];
    int m = end - base;
    if (m > 64) m = 64;
    int mm4 = (m + 3) & ~3;
    for (int k = 0; k < mm4; k += 4) {
      int ek[4], sk[4];
      float exk[4], msk[4], efh[2], exh[2];
#pragma unroll
      for (int u = 0; u < 4; ++u) {
        unsigned lo = (unsigned)__shfl(md.x, k + u);
        unsigned hi = (unsigned)__shfl(md.y, k + u);
        ek[u] = (int)(hi >> 11);
        sk[u] = (int)(((hi & 0x7FFu) << 6) | (lo >> 26));
        exk[u] = __uint_as_float((lo & 0x3FFFFFFu) << 6);
      }
      int eh0 = half ? ek[1] : ek[0];
      int eh1 = half ? ek[3] : ek[2];
      exh[0] = half ? exk[1] : exk[0];
      exh[1] = half ? exk[3] : exk[2];
#pragma unroll
      for (int u = 0; u < 4; ++u)
        msk[u] = m_src[(size_t)sk[u] * NF + lane];
      efh[0] = e_feat[(size_t)eh0 * EF + col];
      efh[1] = e_feat[(size_t)eh1 * EF + col];
#pragma unroll
      for (int u = 0; u < 4; ++u) {
        sum_ex += exk[u];
        acc_ms = fmaf(exk[u], msk[u], acc_ms);
      }
      acc_ef = fmaf(exh[0], efh[0], acc_ef);
      acc_ef = fmaf(exh[1], efh[1], acc_ef);
    }
  }
  // acc_ef[j] = lane j + lane j+32 ; mm[lane] = sum_j Wme[lane][j]*acc_ef[j]
  float mm = 0.f;
#pragma unroll
  for (int j = 0; j < 32; ++j) {
    float efj = __shfl(acc_ef, j) + __shfl(acc_ef, j + 32);
    mm = fmaf(WmeT[j * 64 + lane], efj, mm);
  }
  float o = 0.f;
  if (sum_ex > 0.f) {
    o = (acc_ms + mm) / sum_ex + m_dst[(size_t)n * NF + lane] + Wmsg_b[lane];
    o = fmaxf(o, 0.f);
  }
  out[(size_t)n * NF + lane] = o;
}

extern "C" void kernel_launch(void* const* d_in, const int* in_sizes, int n_in,
                              void* d_out, int out_size, void* d_ws,
                              size_t ws_size, hipStream_t stream) {
  const float* n_feat = (const float*)d_in[0];
  const float* e_feat = (const float*)d_in[1];
  const int* src = (const int*)d_in[2];
  const int* dst = (const int*)d_in[3];
  const float* Wmsg_w = (const float*)d_in[4];
  const float* Wmsg_b = (const float*)d_in[5];
  const float* W_w = (const float*)d_in[6];
  const float* W_b = (const float*)d_in[7];
  const float* a = (const float*)d_in[8];
  float* out = (float*)d_out;

  char* ws = (char*)d_ws;
  size_t off = 0;
  auto alloc = [&](size_t bytes) -> char* {
    char* p = ws + off;
    off = (off + bytes + 255) & ~(size_t)255;
    return p;
  };
  float* v = (float*)alloc(161 * 4);
  float* W1T = (float*)alloc(64 * 64 * 4);
  float* W2T = (float*)alloc(64 * 64 * 4);
  float* WmeT = (float*)alloc(32 * 64 * 4);
  float* s1 = (float*)alloc(N_NODES * 4);
  float* s2 = (float*)alloc(N_NODES * 4);
  float* m_src = (float*)alloc((size_t)N_NODES * NF * 4);
  float* m_dst = (float*)alloc((size_t)N_NODES * NF * 4);
  int* cnt = (int*)alloc(N_NODES * 4);
  int* row_ptr = (int*)alloc((N_NODES + 1) * 4);
  int* cursor = (int*)alloc(N_NODES * 4);
  int* bsum = (int*)alloc(SCAN_NB * 4);
  int* boff = (int*)alloc(SCAN_NB * 4);
  unsigned long long* edata = (unsigned long long*)alloc((size_t)N_EDGES * 8);
  if (off > ws_size) return;  // workspace too small — fail loudly in check

  k0_prep<<<1, 256, 0, stream>>>(W_w, W_b, a, Wmsg_w, v, W1T, W2T, WmeT);
  k1_node<<<(N_NODES + 255) / 256, 256, 0, stream>>>(n_feat, v, W1T, W2T, s1,
                                                     s2, m_src, m_dst);
  hipMemsetAsync(cnt, 0, N_NODES * 4, stream);
  k_count<<<(N_EDGES + 255) / 256, 256, 0, stream>>>(dst, cnt);
  kS1<<<SCAN_NB, SCAN_B, 0, stream>>>(cnt, bsum);
  kS2<<<1, 256, 0, stream>>>(bsum, boff, row_ptr);
  kS3<<<SCAN_NB, SCAN_B, 0, stream>>>(cnt, boff, row_ptr, cursor);
  kE_scatter<<<(N_EDGES + 255) / 256, 256, 0, stream>>>(src, dst, e_feat, s1,
                                                        s2, v, cursor, edata);
  k3_agg<<<(N_NODES + 3) / 4, 256, 0, stream>>>(row_ptr, (const int2*)edata,
                                                e_feat, m_src, m_dst, WmeT,
                                                Wmsg_b, out);
}